// Round 1
// baseline (264.372 us; speedup 1.0000x reference)
//
#include <hip/hip_runtime.h>
#include <math.h>

#define B_  2048
#define T_  200
#define D_  64
#define H1_ 80
#define H2_ 40

__device__ __forceinline__ float sigmoidf_(float x) { return 1.0f / (1.0f + __expf(-x)); }

__global__ __launch_bounds__(256, 2)
void attn_din_kernel(const float* __restrict__ query,
                     const float* __restrict__ key,
                     const int*   __restrict__ mask,
                     const float* __restrict__ W1,
                     const float* __restrict__ b1,
                     const float* __restrict__ W2,
                     const float* __restrict__ b2,
                     const float* __restrict__ W3,
                     const float* __restrict__ b3,
                     float* __restrict__ out)
{
    __shared__ float s_q[D_];
    __shared__ float s_V[H1_ * D_];    // V[h][f] at s_V[h*64+f]  (20 KB)
    __shared__ float s_base[H1_];
    __shared__ float s_W2[H1_ * H2_];  // 12.8 KB
    __shared__ float s_W3[H2_];
    __shared__ float s_b2[H2_];
    __shared__ float s_sc[256];
    __shared__ float s_red[8];
    __shared__ float s_part[4][D_];

    const int b    = blockIdx.x;
    const int tid  = threadIdx.x;
    const int lane = tid & 63;
    const int w    = tid >> 6;

    // ---- stage shared data ----
    if (tid < D_) s_q[tid] = query[b * D_ + tid];
    for (int i = tid; i < H1_ * H2_; i += 256) s_W2[i] = W2[i];
    if (tid < H2_) { s_W3[tid] = W3[tid]; s_b2[tid] = b2[tid]; }
    const int   mv  = mask[b];
    const float b3v = b3[0];
    __syncthreads();

    // ---- per-block effective weights: V[h][f], base[h] ----
    // din = [q, k, q-k, q*k]  =>  pre1 = base + k . V
    #pragma unroll
    for (int i = 0; i < 20; ++i) {
        int e = tid + 256 * i;           // 5120 elements
        int h = e >> 6, f = e & 63;
        float qf = s_q[f];
        s_V[h * D_ + f] = W1[(64 + f) * H1_ + h] - W1[(128 + f) * H1_ + h]
                        + qf * W1[(192 + f) * H1_ + h];
    }
    if (tid < H1_) {
        float a = b1[tid];
        for (int f = 0; f < D_; ++f)
            a = fmaf(s_q[f], W1[f * H1_ + tid] + W1[(128 + f) * H1_ + tid], a);
        s_base[tid] = a;
    }
    __syncthreads();

    // ---- scoring MLP: thread t handles row t ----
    float score = -1e30f;
    if (tid < T_) {
        float kk[D_];
        const float4* kp = (const float4*)(key + ((size_t)b * T_ + tid) * D_);
        #pragma unroll
        for (int i = 0; i < 16; ++i) {
            float4 v = kp[i];
            kk[4*i+0] = v.x; kk[4*i+1] = v.y; kk[4*i+2] = v.z; kk[4*i+3] = v.w;
        }

        float acc2[H2_];
        #pragma unroll
        for (int g = 0; g < H2_; ++g) acc2[g] = s_b2[g];

        for (int h = 0; h < H1_; ++h) {
            float a = s_base[h];
            const float4* vr = (const float4*)&s_V[h * D_];
            #pragma unroll
            for (int f4 = 0; f4 < 16; ++f4) {
                float4 v = vr[f4];
                a = fmaf(kk[4*f4+0], v.x, a);
                a = fmaf(kk[4*f4+1], v.y, a);
                a = fmaf(kk[4*f4+2], v.z, a);
                a = fmaf(kk[4*f4+3], v.w, a);
            }
            float h1v = sigmoidf_(a);
            const float4* w2r = (const float4*)&s_W2[h * H2_];
            #pragma unroll
            for (int g4 = 0; g4 < 10; ++g4) {
                float4 wv = w2r[g4];
                acc2[4*g4+0] = fmaf(h1v, wv.x, acc2[4*g4+0]);
                acc2[4*g4+1] = fmaf(h1v, wv.y, acc2[4*g4+1]);
                acc2[4*g4+2] = fmaf(h1v, wv.z, acc2[4*g4+2]);
                acc2[4*g4+3] = fmaf(h1v, wv.w, acc2[4*g4+3]);
            }
        }
        float sc = b3v;
        #pragma unroll
        for (int g = 0; g < H2_; ++g) sc = fmaf(sigmoidf_(acc2[g]), s_W3[g], sc);
        // reference: mask to NEG_INF, then scale by 1/sqrt(64); exp -> 0 either way
        score = (tid < mv) ? sc * 0.125f : -1e30f;
    }

    // ---- softmax over 256 slots (t >= 200 and masked are -1e30 -> p = 0) ----
    float v = score;
    #pragma unroll
    for (int off = 32; off >= 1; off >>= 1) v = fmaxf(v, __shfl_xor(v, off));
    if (lane == 0) s_red[w] = v;
    __syncthreads();
    float m = fmaxf(fmaxf(s_red[0], s_red[1]), fmaxf(s_red[2], s_red[3]));
    float p = __expf(score - m);
    float ps = p;
    #pragma unroll
    for (int off = 32; off >= 1; off >>= 1) ps += __shfl_xor(ps, off);
    if (lane == 0) s_red[4 + w] = ps;
    s_sc[tid] = p;
    __syncthreads();
    float inv_total = 1.0f / (s_red[4] + s_red[5] + s_red[6] + s_red[7]);

    // ---- weighted sum: out[b][d] = sum_t attn[t] * key[b][t][d] ----
    float acc = 0.0f;
    const float* kb = key + (size_t)b * T_ * D_;
    for (int t = w * 50; t < w * 50 + 50; ++t)
        acc = fmaf(s_sc[t], kb[t * D_ + lane], acc);
    s_part[w][lane] = acc;
    __syncthreads();
    if (tid < D_) {
        float r = (s_part[0][tid] + s_part[1][tid] + s_part[2][tid] + s_part[3][tid]) * inv_total;
        out[b * D_ + tid] = r;
    }
}

extern "C" void kernel_launch(void* const* d_in, const int* in_sizes, int n_in,
                              void* d_out, int out_size, void* d_ws, size_t ws_size,
                              hipStream_t stream)
{
    const float* query = (const float*)d_in[0];
    const float* key   = (const float*)d_in[1];
    const int*   mask  = (const int*)  d_in[2];
    const float* W1    = (const float*)d_in[3];
    const float* b1    = (const float*)d_in[4];
    const float* W2    = (const float*)d_in[5];
    const float* b2    = (const float*)d_in[6];
    const float* W3    = (const float*)d_in[7];
    const float* b3    = (const float*)d_in[8];
    float* out = (float*)d_out;

    attn_din_kernel<<<B_, 256, 0, stream>>>(query, key, mask, W1, b1, W2, b2, W3, b3, out);
}

// Round 2
// 90.766 us; speedup vs baseline: 2.9127x; 2.9127x over previous
//
#include <hip/hip_runtime.h>
#include <math.h>

#define B_  2048
#define T_  200
#define D_  64
#define H1_ 80
#define H2_ 40

// LDS row strides (in bf16 elements), padded to avoid power-of-2 bank conflicts
#define KSTR 72    // K-tile view: 144 B rows -> 2-way max on A-frag reads
#define HSTR 104   // h1 / W2T view: 208 B rows -> 2-way max (also holds K=96 padded)

typedef __bf16 bf16x8 __attribute__((ext_vector_type(8)));
typedef __bf16 bf16x4 __attribute__((ext_vector_type(4)));
typedef float  f32x4  __attribute__((ext_vector_type(4)));

__device__ __forceinline__ float sigmoidf_(float x) { return 1.0f / (1.0f + __expf(-x)); }

__global__ __launch_bounds__(256, 2)
void attn_din_mfma(const float* __restrict__ query,
                   const float* __restrict__ key,
                   const int*   __restrict__ mask,
                   const float* __restrict__ W1,
                   const float* __restrict__ b1,
                   const float* __restrict__ W2,
                   const float* __restrict__ b2,
                   const float* __restrict__ W3,
                   const float* __restrict__ b3,
                   float* __restrict__ out)
{
    // 53248 B union buffer: K-tile [256][KSTR] bf16, later h1 [256][HSTR] bf16
    __shared__ __bf16 s_KH[256 * HSTR];
    __shared__ __bf16 s_V[H1_ * KSTR];      // V[h][f] (B operand of layer1)
    __shared__ __bf16 s_W2T[48 * HSTR];     // W2T[g][h], zero-padded g>=40, h>=80
    __shared__ float  s_q[D_];
    __shared__ float  s_base[H1_];
    __shared__ float  s_W3[48];
    __shared__ float  s_b2[48];
    __shared__ float  s_scf[256];
    __shared__ float  s_red[8];
    __shared__ float  s_part[4][D_];

    const int b    = blockIdx.x;
    const int tid  = threadIdx.x;
    const int lane = tid & 63;
    const int w    = tid >> 6;     // wave id 0..3; owns m-tiles 4w..4w+3 (rows 64w..64w+63)
    const int c16  = lane & 15;    // MFMA col group
    const int g16  = lane >> 4;    // MFMA k/row group

    const int   mv  = mask[b];
    const float b3v = b3[0];

    // ---------------- phase 1: q, W2T, W3/b2, K-tile staging ----------------
    if (tid < D_) s_q[tid] = query[b * D_ + tid];
    if (tid < 48) {
        s_W3[tid] = (tid < H2_) ? W3[tid] : 0.0f;
        s_b2[tid] = (tid < H2_) ? b2[tid] : 0.0f;
    }
    #pragma unroll
    for (int i = 0; i < 20; ++i) {
        int e = tid + 256 * i;                 // 48*HSTR = 4992 elements
        if (e < 48 * HSTR) {
            int g = e / HSTR, h = e % HSTR;
            float v = (g < H2_ && h < H1_) ? W2[h * H2_ + g] : 0.0f;
            s_W2T[g * HSTR + h] = (__bf16)v;
        }
    }
    const float* kb = key + (size_t)b * T_ * D_;
    #pragma unroll
    for (int i = 0; i < 13; ++i) {
        int e = tid + 256 * i;                 // 200 rows * 16 float4 = 3200
        if (e < T_ * 16) {
            int row = e >> 4, c4 = e & 15;
            float4 v = *(const float4*)(kb + row * D_ + c4 * 4);
            bf16x4 pk;
            pk[0] = (__bf16)v.x; pk[1] = (__bf16)v.y;
            pk[2] = (__bf16)v.z; pk[3] = (__bf16)v.w;
            *(bf16x4*)&s_KH[row * KSTR + c4 * 4] = pk;
        }
    }
    #pragma unroll
    for (int i = 0; i < 4; ++i) {
        int e = tid + 256 * i;                 // zero rows 200..255: 56*16 = 896
        if (e < 896) {
            int row = 200 + (e >> 4), c4 = e & 15;
            bf16x4 z; z[0] = z[1] = z[2] = z[3] = (__bf16)0.0f;
            *(bf16x4*)&s_KH[row * KSTR + c4 * 4] = z;
        }
    }
    __syncthreads();

    // ---------------- phase 2: collapsed weights V[h][f], base[h] ----------------
    // din=[q,k,q-k,q*k] => pre1[t][h] = base[h] + sum_f k[t][f]*V[h][f]
    #pragma unroll
    for (int i = 0; i < 20; ++i) {
        int e = tid + 256 * i;                 // 5120 exactly
        int h = e % H1_, f = e / H1_;
        float v = W1[(64 + f) * H1_ + h] - W1[(128 + f) * H1_ + h]
                + s_q[f] * W1[(192 + f) * H1_ + h];
        s_V[h * KSTR + f] = (__bf16)v;
    }
    if (tid < H1_) {
        float a = b1[tid];
        for (int f = 0; f < D_; ++f)
            a = fmaf(s_q[f], W1[f * H1_ + tid] + W1[(128 + f) * H1_ + tid], a);
        s_base[tid] = a;
    }
    __syncthreads();

    // ---------------- layer 1: (256x64) @ (64x80) via MFMA ----------------
    // A frag (16x16x32): lane -> row = c16, k = g16*8..+8 ; C/D: col=c16, row=g16*4+reg
    bf16x8 af[4][2], bf[5][2];
    #pragma unroll
    for (int mt = 0; mt < 4; ++mt)
        #pragma unroll
        for (int ks = 0; ks < 2; ++ks)
            af[mt][ks] = *(const bf16x8*)&s_KH[((w * 4 + mt) * 16 + c16) * KSTR + ks * 32 + g16 * 8];
    #pragma unroll
    for (int nt = 0; nt < 5; ++nt)
        #pragma unroll
        for (int ks = 0; ks < 2; ++ks)
            bf[nt][ks] = *(const bf16x8*)&s_V[(nt * 16 + c16) * KSTR + ks * 32 + g16 * 8];
    __syncthreads();   // all waves done reading K-tile; s_KH may be overwritten with h1

    f32x4 acc1[4][5];
    #pragma unroll
    for (int mt = 0; mt < 4; ++mt)
        #pragma unroll
        for (int nt = 0; nt < 5; ++nt) {
            float bb = s_base[nt * 16 + c16];
            f32x4 c = { bb, bb, bb, bb };
            c = __builtin_amdgcn_mfma_f32_16x16x32_bf16(af[mt][0], bf[nt][0], c, 0, 0, 0);
            c = __builtin_amdgcn_mfma_f32_16x16x32_bf16(af[mt][1], bf[nt][1], c, 0, 0, 0);
            acc1[mt][nt] = c;
        }

    // sigmoid -> h1 into s_KH at stride HSTR (bf16), plus zero-pad k=80..95
    #pragma unroll
    for (int mt = 0; mt < 4; ++mt)
        #pragma unroll
        for (int nt = 0; nt < 5; ++nt)
            #pragma unroll
            for (int r = 0; r < 4; ++r) {
                int t = (w * 4 + mt) * 16 + g16 * 4 + r;
                s_KH[t * HSTR + nt * 16 + c16] = (__bf16)sigmoidf_(acc1[mt][nt][r]);
            }
    {
        int row = w * 64 + lane;               // each wave pads its own 64 rows
        *(uint4*)&s_KH[row * HSTR + 80] = make_uint4(0, 0, 0, 0);
        *(uint4*)&s_KH[row * HSTR + 88] = make_uint4(0, 0, 0, 0);
    }
    __syncthreads();

    // ---------------- layer 2: (256x96) @ (96x48) via MFMA, layer 3 in-register ----------------
    bf16x8 a2[4][3], bw[3][3];
    #pragma unroll
    for (int mt = 0; mt < 4; ++mt)
        #pragma unroll
        for (int ks = 0; ks < 3; ++ks)
            a2[mt][ks] = *(const bf16x8*)&s_KH[((w * 4 + mt) * 16 + c16) * HSTR + ks * 32 + g16 * 8];
    #pragma unroll
    for (int nt = 0; nt < 3; ++nt)
        #pragma unroll
        for (int ks = 0; ks < 3; ++ks)
            bw[nt][ks] = *(const bf16x8*)&s_W2T[(nt * 16 + c16) * HSTR + ks * 32 + g16 * 8];

    float w3c[3] = { s_W3[c16], s_W3[16 + c16], s_W3[32 + c16] };
    #pragma unroll
    for (int mt = 0; mt < 4; ++mt) {
        f32x4 acc2[3];
        #pragma unroll
        for (int nt = 0; nt < 3; ++nt) {
            float bb = s_b2[nt * 16 + c16];
            f32x4 c = { bb, bb, bb, bb };
            c = __builtin_amdgcn_mfma_f32_16x16x32_bf16(a2[mt][0], bw[nt][0], c, 0, 0, 0);
            c = __builtin_amdgcn_mfma_f32_16x16x32_bf16(a2[mt][1], bw[nt][1], c, 0, 0, 0);
            c = __builtin_amdgcn_mfma_f32_16x16x32_bf16(a2[mt][2], bw[nt][2], c, 0, 0, 0);
            acc2[nt] = c;
        }
        #pragma unroll
        for (int r = 0; r < 4; ++r) {
            float partial = sigmoidf_(acc2[0][r]) * w3c[0]
                          + sigmoidf_(acc2[1][r]) * w3c[1]
                          + sigmoidf_(acc2[2][r]) * w3c[2];
            partial += __shfl_xor(partial, 1);
            partial += __shfl_xor(partial, 2);
            partial += __shfl_xor(partial, 4);
            partial += __shfl_xor(partial, 8);
            if (c16 == 0) {
                int t = (w * 4 + mt) * 16 + g16 * 4 + r;
                float sc = (partial + b3v) * 0.125f;   // / sqrt(64)
                s_scf[t] = (t < mv) ? sc : -1e30f;
            }
        }
    }
    __syncthreads();

    // ---------------- softmax over 256 slots ----------------
    float score = s_scf[tid];
    float v = score;
    #pragma unroll
    for (int off = 32; off >= 1; off >>= 1) v = fmaxf(v, __shfl_xor(v, off));
    if (lane == 0) s_red[w] = v;
    __syncthreads();
    float m = fmaxf(fmaxf(s_red[0], s_red[1]), fmaxf(s_red[2], s_red[3]));
    float p = __expf(score - m);
    float ps = p;
    #pragma unroll
    for (int off = 32; off >= 1; off >>= 1) ps += __shfl_xor(ps, off);
    if (lane == 0) s_red[4 + w] = ps;
    s_scf[tid] = p;
    __syncthreads();
    float inv_total = 1.0f / (s_red[4] + s_red[5] + s_red[6] + s_red[7]);

    // ---------------- weighted sum: out[b][d] = sum_t p[t]*key[b][t][d] ----------------
    float acc = 0.0f;
    for (int t = w * 50; t < w * 50 + 50; ++t)
        acc = fmaf(s_scf[t], kb[t * D_ + lane], acc);
    s_part[w][lane] = acc;
    __syncthreads();
    if (tid < D_) {
        float r = (s_part[0][tid] + s_part[1][tid] + s_part[2][tid] + s_part[3][tid]) * inv_total;
        out[b * D_ + tid] = r;
    }
}

extern "C" void kernel_launch(void* const* d_in, const int* in_sizes, int n_in,
                              void* d_out, int out_size, void* d_ws, size_t ws_size,
                              hipStream_t stream)
{
    const float* query = (const float*)d_in[0];
    const float* key   = (const float*)d_in[1];
    const int*   mask  = (const int*)  d_in[2];
    const float* W1    = (const float*)d_in[3];
    const float* b1    = (const float*)d_in[4];
    const float* W2    = (const float*)d_in[5];
    const float* b2    = (const float*)d_in[6];
    const float* W3    = (const float*)d_in[7];
    const float* b3    = (const float*)d_in[8];
    float* out = (float*)d_out;

    attn_din_mfma<<<B_, 256, 0, stream>>>(query, key, mask, W1, b1, W2, b2, W3, b3, out);
}